// Round 3
// baseline (4904.749 us; speedup 1.0000x reference)
//
#include <hip/hip_runtime.h>
#include <hip/hip_bf16.h>

#define BB 128
#define TT 150
#define DD 100
#define TS 149
#define NITEM (TS*BB)

__device__ __forceinline__ float bf(__hip_bfloat16 x) { return __bfloat162float(x); }
__device__ __forceinline__ __hip_bfloat16 tobf(float x) { return __float2bfloat16(x); }
__device__ __forceinline__ float sigm(float x) { return 1.f / (1.f + expf(-x)); }

// ---------------------------------------------------------------------------
// P1: per-(t,b) multi-hop aggregate -> emb_hat  (index-only, fully parallel)
// ---------------------------------------------------------------------------
__global__ __launch_bounds__(512, 1) void k_embhat(
    const float* __restrict__ emb_q, const float* __restrict__ emb_q2,
    const float* __restrict__ emb_s, const float* __restrict__ emb_u,
    const float* __restrict__ w1_q, const float* __restrict__ w2_q,
    const float* __restrict__ agg_W, const float* __restrict__ agg_b,
    const float* __restrict__ last_W, const float* __restrict__ last_b,
    const int* __restrict__ user, const int* __restrict__ question, const int* __restrict__ mask,
    const int* __restrict__ q_nb, const int* __restrict__ s_nb,
    const int* __restrict__ u_nb, const int* __restrict__ q_nb2,
    __hip_bfloat16* __restrict__ embhat)
{
  __shared__ __hip_bfloat16 W0T[10000], W1T[10000], W2T[10000], WLT[10000];
  __shared__ float b0[100], b1[100], b2[100], bl[100];
  __shared__ int n1[4], n2[40], n3[160], m1[10], m2[50], m3[500];
  __shared__ float bufA[5000];
  __shared__ float t1a_in[1000], t0a_in[100];
  __shared__ float m2b[1000], t1a[1000], t1b[1000];
  __shared__ float t0a[100], t0b[100], t0c[100], aggq[100];
  const int tid = threadIdx.x;
  // stage weights transposed (WT[k*100+c] = W[c][k]) as bf16 (tolerance is bf16-grade)
  for (int i = tid; i < 10000; i += 512) {
    int c = i / 100, k = i % 100;
    W0T[k*100+c] = tobf(agg_W[i]);
    W1T[k*100+c] = tobf(agg_W[10000 + i]);
    W2T[k*100+c] = tobf(agg_W[20000 + i]);
    WLT[k*100+c] = tobf(last_W[i]);
  }
  if (tid < 100) {
    b0[tid] = agg_b[tid]; b1[tid] = agg_b[100+tid];
    b2[tid] = agg_b[200+tid]; bl[tid] = last_b[tid];
  }
  const float w1 = w1_q[0], w2 = w2_q[0];
  __syncthreads();
  for (int item = blockIdx.x; item < NITEM; item += gridDim.x) {
    const int t = item / BB, b = item % BB;
    const int qt = question[b*TT + t];
    if (mask[b*TT + t] != 1) {
      if (tid < 100) embhat[item*100 + tid] = tobf(w1*emb_q[qt*100+tid] + w2*emb_q2[qt*100+tid]);
      continue;
    }
    const int ut = user[b*TT + t];
    // ---- index staging (3 dependent levels) ----
    if (tid < 4) n1[tid] = q_nb[qt*4 + tid];
    else if (tid >= 64 && tid < 74) m1[tid-64] = u_nb[ut*10 + (tid-64)];
    __syncthreads();
    if (tid < 40) n2[tid] = s_nb[n1[tid/10]*10 + tid%10];
    else if (tid >= 64 && tid < 114) { int e = tid-64; m2[e] = q_nb2[m1[e/5]*5 + e%5]; }
    __syncthreads();
    for (int i = tid; i < 660; i += 512) {
      if (i < 160) n3[i] = q_nb[n2[i/4]*4 + i%4];
      else { int e = i-160; m3[e] = u_nb[m2[e/10]*10 + e%10]; }
    }
    __syncthreads();
    // ================= question side =================
    // A: level inputs (mean(next hop) + this hop)
    for (int u = tid; u < 4500; u += 512) {
      if (u < 4000) {
        int r = u/100, c = u%100;
        float s = emb_s[n3[r*4+0]*100+c] + emb_s[n3[r*4+1]*100+c]
                + emb_s[n3[r*4+2]*100+c] + emb_s[n3[r*4+3]*100+c];
        bufA[r*100+c] = 0.25f*s + emb_q[n2[r]*100+c];
      } else if (u < 4400) {
        int e = u-4000, a = e/100, c = e%100;
        float s = 0.f;
        for (int j = 0; j < 10; j++) s += emb_q[n2[a*10+j]*100+c];
        t1a_in[a*100+c] = 0.1f*s + emb_s[n1[a]*100+c];
      } else {
        int c = u-4400;
        float s = emb_s[n1[0]*100+c] + emb_s[n1[1]*100+c]
                + emb_s[n1[2]*100+c] + emb_s[n1[3]*100+c];
        t0a_in[c] = 0.25f*s + emb_q[qt*100+c];
      }
    }
    __syncthreads();
    // B: h2' mean (fused relu+mean), h1', h0'
    for (int u = tid; u < 900; u += 512) {
      if (u < 400) {
        int a = u/100, c = u%100;
        float acc = 0.f;
        for (int s = 0; s < 10; s++) {
          const float* x = &bufA[(a*10+s)*100];
          float d = b2[c];
          for (int k = 0; k < 100; k++) d += bf(W2T[k*100+c]) * x[k];
          acc += fmaxf(d, 0.f);
        }
        m2b[a*100+c] = 0.1f*acc;
      } else if (u < 800) {
        int e = u-400, a = e/100, c = e%100;
        float d = b1[c];
        for (int k = 0; k < 100; k++) d += bf(W1T[k*100+c]) * t1a_in[a*100+k];
        t1a[a*100+c] = fmaxf(d, 0.f);
      } else {
        int c = u-800;
        float d = b0[c];
        for (int k = 0; k < 100; k++) d += bf(W0T[k*100+c]) * t0a_in[k];
        t0a[c] = fmaxf(d, 0.f);
      }
    }
    __syncthreads();
    // C: h1'' = L1(mean(h2')+h1'), h0'' = L0(mean4(h1')+h0')
    for (int u = tid; u < 500; u += 512) {
      if (u < 400) {
        int a = u/100, c = u%100;
        float d = b1[c];
        for (int k = 0; k < 100; k++) d += bf(W1T[k*100+c]) * (m2b[a*100+k] + t1a[a*100+k]);
        t1b[a*100+c] = fmaxf(d, 0.f);
      } else {
        int c = u-400;
        float d = b0[c];
        for (int k = 0; k < 100; k++)
          d += bf(W0T[k*100+c]) * (0.25f*(t1a[k]+t1a[100+k]+t1a[200+k]+t1a[300+k]) + t0a[k]);
        t0b[c] = fmaxf(d, 0.f);
      }
    }
    __syncthreads();
    // D: h0''' = L0(mean4(h1'')+h0'')
    if (tid < 100) {
      int c = tid;
      float d = b0[c];
      for (int k = 0; k < 100; k++)
        d += bf(W0T[k*100+c]) * (0.25f*(t1b[k]+t1b[100+k]+t1b[200+k]+t1b[300+k]) + t0b[k]);
      t0c[c] = fmaxf(d, 0.f);
    }
    __syncthreads();
    // E: agg1 = relu(Llast(h0'''))
    if (tid < 100) {
      int c = tid;
      float d = bl[c];
      for (int k = 0; k < 100; k++) d += bf(WLT[k*100+c]) * t0c[k];
      aggq[c] = fmaxf(d, 0.f);
    }
    __syncthreads();
    // ================= user side (UNB=10, Q2NB=5) =================
    for (int u = tid; u < 6100; u += 512) {
      if (u < 5000) {
        int r = u/100, c = u%100;
        float s = 0.f;
        for (int k = 0; k < 10; k++) s += emb_q2[m3[r*10+k]*100+c];
        bufA[r*100+c] = 0.1f*s + emb_u[m2[r]*100+c];
      } else if (u < 6000) {
        int e = u-5000, a = e/100, c = e%100;
        float s = 0.f;
        for (int p = 0; p < 5; p++) s += emb_u[m2[a*5+p]*100+c];
        t1a_in[a*100+c] = 0.2f*s + emb_q2[m1[a]*100+c];
      } else {
        int c = u-6000;
        float s = 0.f;
        for (int mm = 0; mm < 10; mm++) s += emb_q2[m1[mm]*100+c];
        t0a_in[c] = 0.1f*s + emb_u[ut*100+c];
      }
    }
    __syncthreads();
    for (int u = tid; u < 2100; u += 512) {
      if (u < 1000) {
        int a = u/100, c = u%100;
        float acc = 0.f;
        for (int p = 0; p < 5; p++) {
          const float* x = &bufA[(a*5+p)*100];
          float d = b2[c];
          for (int k = 0; k < 100; k++) d += bf(W2T[k*100+c]) * x[k];
          acc += fmaxf(d, 0.f);
        }
        m2b[a*100+c] = 0.2f*acc;
      } else if (u < 2000) {
        int e = u-1000, a = e/100, c = e%100;
        float d = b1[c];
        for (int k = 0; k < 100; k++) d += bf(W1T[k*100+c]) * t1a_in[a*100+k];
        t1a[a*100+c] = fmaxf(d, 0.f);
      } else {
        int c = u-2000;
        float d = b0[c];
        for (int k = 0; k < 100; k++) d += bf(W0T[k*100+c]) * t0a_in[k];
        t0a[c] = fmaxf(d, 0.f);
      }
    }
    __syncthreads();
    for (int u = tid; u < 1100; u += 512) {
      if (u < 1000) {
        int a = u/100, c = u%100;
        float d = b1[c];
        for (int k = 0; k < 100; k++) d += bf(W1T[k*100+c]) * (m2b[a*100+k] + t1a[a*100+k]);
        t1b[a*100+c] = fmaxf(d, 0.f);
      } else {
        int c = u-1000;
        float d = b0[c];
        for (int k = 0; k < 100; k++) {
          float s = 0.f;
          for (int mm = 0; mm < 10; mm++) s += t1a[mm*100+k];
          d += bf(W0T[k*100+c]) * (0.1f*s + t0a[k]);
        }
        t0b[c] = fmaxf(d, 0.f);
      }
    }
    __syncthreads();
    if (tid < 100) {
      int c = tid;
      float d = b0[c];
      for (int k = 0; k < 100; k++) {
        float s = 0.f;
        for (int mm = 0; mm < 10; mm++) s += t1b[mm*100+k];
        d += bf(W0T[k*100+c]) * (0.1f*s + t0b[k]);
      }
      t0c[c] = fmaxf(d, 0.f);
    }
    __syncthreads();
    if (tid < 100) {
      int c = tid;
      float d = bl[c];
      for (int k = 0; k < 100; k++) d += bf(WLT[k*100+c]) * t0c[k];
      embhat[item*100 + c] = tobf(w1*aggq[c] + w2*fmaxf(d, 0.f));
    }
    __syncthreads();
  }
}

// ---------------------------------------------------------------------------
// P2a: x_in = relu(lin([emb_hat, emb_r[r_t]]))
// ---------------------------------------------------------------------------
__global__ __launch_bounds__(256, 1) void k_xin(
    const float* __restrict__ emb_r, const float* __restrict__ lin_W,
    const float* __restrict__ lin_b, const int* __restrict__ response,
    const __hip_bfloat16* __restrict__ embhat, __hip_bfloat16* __restrict__ xin)
{
  __shared__ __hip_bfloat16 WT[40000];
  __shared__ float xcat[200];
  __shared__ float lb[200];
  const int tid = threadIdx.x;
  for (int i = tid; i < 40000; i += 256) { int j = i/200, k = i%200; WT[k*200+j] = tobf(lin_W[i]); }
  if (tid < 200) lb[tid] = lin_b[tid];
  __syncthreads();
  for (int item = blockIdx.x; item < NITEM; item += gridDim.x) {
    const int t = item / BB, b = item % BB;
    if (tid < 100) xcat[tid] = bf(embhat[item*100 + tid]);
    else if (tid < 200) { int rt = response[b*TT + t]; xcat[tid] = emb_r[rt*100 + tid - 100]; }
    __syncthreads();
    if (tid < 200) {
      float acc = lb[tid];
      for (int k = 0; k < 200; k++) acc += bf(WT[k*200+tid]) * xcat[k];
      xin[item*200 + tid] = tobf(fmaxf(acc, 0.f));
    }
    __syncthreads();
  }
}

// ---------------------------------------------------------------------------
// P2b: xg = x_in @ Wih.T + bih + bhh   (blockIdx.y selects output half)
// ---------------------------------------------------------------------------
__global__ __launch_bounds__(256, 1) void k_xg(
    const float* __restrict__ Wih, const float* __restrict__ bih,
    const float* __restrict__ bhh,
    const __hip_bfloat16* __restrict__ xin, __hip_bfloat16* __restrict__ xg)
{
  __shared__ __hip_bfloat16 WT[40000];
  __shared__ float xv[200];
  __shared__ float bsum[200];
  const int tid = threadIdx.x;
  const int H = blockIdx.y;
  for (int i = tid; i < 40000; i += 256) { int jj = i/200, k = i%200; WT[k*200+jj] = tobf(Wih[H*40000 + i]); }
  if (tid < 200) bsum[tid] = bih[H*200+tid] + bhh[H*200+tid];
  __syncthreads();
  for (int item = blockIdx.x; item < NITEM; item += gridDim.x) {
    if (tid < 200) xv[tid] = bf(xin[item*200 + tid]);
    __syncthreads();
    if (tid < 200) {
      float acc = bsum[tid];
      for (int k = 0; k < 200; k++) acc += bf(WT[k*200+tid]) * xv[k];
      xg[(long)item*400 + H*200 + tid] = tobf(acc);
    }
    __syncthreads();
  }
}

// ---------------------------------------------------------------------------
// P3: per-(b,t) top-10 of dot(eq[question[b,t+1]], eq[question[b,j]]), j<t
// ---------------------------------------------------------------------------
__global__ __launch_bounds__(256, 2) void k_topk(
    const float* __restrict__ emb_q, const int* __restrict__ question,
    int* __restrict__ topidx)
{
  __shared__ float Qb[150*101];
  __shared__ int qid[150];
  __shared__ float tval[1490];
  __shared__ int tidxs[1490];
  const int b = blockIdx.x, tid = threadIdx.x;
  if (tid < 150) qid[tid] = question[b*TT + tid];
  __syncthreads();
  for (int i = tid; i < 15000; i += 256) { int r = i/100, c = i%100; Qb[r*101+c] = emb_q[qid[r]*100+c]; }
  __syncthreads();
  if (tid < TS) {
    const int t = tid;
    float* v = &tval[t*10]; int* ix = &tidxs[t*10];
    for (int p = 0; p < 10; p++) { v[p] = -3.0e38f; ix[p] = 0; }
    const float* qrow = &Qb[(t+1)*101];
    for (int j = 0; j < t; j++) {
      const float* r = &Qb[j*101];
      float s = 0.f;
      for (int k = 0; k < 100; k++) s += qrow[k] * r[k];
      if (s > v[9]) {
        int p = 9;
        while (p > 0 && s > v[p-1]) { v[p] = v[p-1]; ix[p] = ix[p-1]; p--; }
        v[p] = s; ix[p] = j;
      }
    }
    for (int p = 0; p < 10; p++) topidx[(t*BB + b)*10 + p] = ix[p];
  }
}

// ---------------------------------------------------------------------------
// P4: the sequential scan — one block per batch element, everything in LDS.
// ---------------------------------------------------------------------------
__global__ __launch_bounds__(512, 1) void k_scan(
    const float* __restrict__ emb_q, const float* __restrict__ emb_s,
    const float* __restrict__ Whh,
    const float* __restrict__ qW, const float* __restrict__ qb,
    const float* __restrict__ kW, const float* __restrict__ kb,
    const float* __restrict__ wW, const float* __restrict__ wb,
    const float* __restrict__ h0, const float* __restrict__ c0,
    const int* __restrict__ question, const int* __restrict__ qs_skill,
    const __hip_bfloat16* __restrict__ xg, const int* __restrict__ topidx,
    float* __restrict__ out)
{
  __shared__ __hip_bfloat16 WhhT[40000];   // [k][j]
  __shared__ float hist[15000];            // [150][100]; row 0 stays zero forever
  __shared__ float h_l[100], c_l[100], gates[400], partial[100];
  __shared__ float qs_l[500], kv[100], qv[100], skv[150], wvec[200];
  __shared__ float gmat[55], sq_l[5];
  __shared__ int selidx[11];
  __shared__ float scal[4]; // 0:ck 1:cq 2:wb0 3:sk(current h)
  const int b = blockIdx.x, tid = threadIdx.x;
  for (int i = tid; i < 40000; i += 512) { int j = i/100, k = i%100; WhhT[k*400+j] = tobf(Whh[i]); }
  for (int i = tid; i < 15000; i += 512) hist[i] = 0.f;
  if (tid < 200) wvec[tid] = wW[tid];
  if (tid < 150) skv[tid] = 0.f;
  if (tid >= 256 && tid < 356) { h_l[tid-256] = h0[b*100+tid-256]; c_l[tid-256] = c0[b*100+tid-256]; }
  __syncthreads();
  if (tid < 100) {
    // sq = qs.qv + cq ; sk = h.kv + ck   (linear-then-dot collapsed)
    float a1 = 0.f, a2 = 0.f;
    for (int c = 0; c < 100; c++) { a1 += kW[c*100+tid] * wvec[100+c]; a2 += qW[c*100+tid] * wvec[c]; }
    kv[tid] = a1; qv[tid] = a2;
  }
  if (tid == 256) {
    float ck = 0.f, cq = 0.f;
    for (int c = 0; c < 100; c++) { ck += kb[c] * wvec[100+c]; cq += qb[c] * wvec[c]; }
    scal[0] = ck; scal[1] = cq; scal[2] = wb[0]; scal[3] = 0.f;
    skv[0] = ck;                 // hist row 0 is the zero vector
    out[b*TT] = 0.5f;            // output column 0
  }
  __syncthreads();
  for (int t = 0; t < TS; t++) {
    // phase 1: gates = xg[t,b] + h @ Whh.T
    if (tid < 400) {
      float acc = bf(xg[((long)t*BB + b)*400 + tid]);
      for (int k = 0; k < 100; k++) acc += bf(WhhT[k*400+tid]) * h_l[k];
      gates[tid] = acc;
    }
    __syncthreads();
    // phase 1b: LSTM pointwise (torch gate order i,f,g,o)
    if (tid < 100) {
      float cc = sigm(gates[100+tid])*c_l[tid] + sigm(gates[tid])*tanhf(gates[200+tid]);
      c_l[tid] = cc;
      float hn = sigm(gates[300+tid])*tanhf(cc);
      h_l[tid] = hn;
      if (t > 0) hist[t*100+tid] = hn;
      partial[tid] = hn * kv[tid];
    }
    __syncthreads();
    // phase 2: sk(current h) reduce | qs_concat staging | selection indices
    if (tid < 64) {
      float v = partial[tid] + ((tid < 36) ? partial[tid+64] : 0.f);
      #pragma unroll
      for (int o = 32; o; o >>= 1) v += __shfl_xor(v, o);
      if (tid == 0) { float s = v + scal[0]; scal[3] = s; if (t > 0) skv[t] = s; }
    } else {
      const int qn = question[b*TT + t + 1];
      for (int e = tid - 64; e < 500; e += 448) {
        int q = e / 100, c = e % 100;
        qs_l[e] = (q == 0) ? emb_q[qn*100 + c] : emb_s[qs_skill[qn*4 + q - 1]*100 + c];
      }
      if (tid < 75) {
        int p = tid - 64;
        if (p == 0) selidx[0] = -2;
        else {
          int pp = p - 1;
          int cnt = t < 10 ? t : 10;      // valid = isfinite(top_vals) = min(t,10)
          selidx[p] = (pp < cnt) ? topidx[((long)t*BB + b)*10 + pp] : -1;
        }
      }
    }
    __syncthreads();
    // phase 3: g[q][s] dots + sq[q] — branchless row select, single shfl site
    {
      int u = tid >> 2, l4 = tid & 3;
      if (u < 60) {
        const float* row;
        int q;
        const bool isG = (u < 55);
        if (isG) {
          q = u / 11;
          int s = u % 11;
          int j = (s == 0) ? 0 : selidx[s];
          if (j < 0) j = 0;               // hist row 0 == zeros -> g contribution 0
          row = (s == 0) ? h_l : &hist[j*100];
        } else { q = u - 55; row = qv; }
        float part = 0.f;
        for (int k = l4*25; k < l4*25+25; k++) part += qs_l[q*100+k] * row[k];
        part += __shfl_xor(part, 1);
        part += __shfl_xor(part, 2);
        if (l4 == 0) { if (isG) gmat[u] = part; else sq_l[q] = part + scal[1]; }
      }
    }
    __syncthreads();
    // phase 4: masked softmax over 55 + y (wave 0 only) — branchless
    if (tid < 64) {
      const bool has = (tid < 55);
      int q = has ? tid/11 : 0, s = has ? tid%11 : 0;
      int j = (s == 0) ? 0 : selidx[s];
      bool valid = has && ((s == 0) || (j >= 0));
      if (j < 0) j = 0;
      float sk = (s == 0) ? scal[3] : skv[j];
      float sc = valid ? (sq_l[q] + sk + scal[2]) : -1e9f;
      float gv = has ? gmat[tid] : 0.f;
      float m = sc;
      #pragma unroll
      for (int o = 32; o; o >>= 1) m = fmaxf(m, __shfl_xor(m, o));
      float ex = has ? expf(sc - m) : 0.f;
      float num = ex * gv, den = ex;
      #pragma unroll
      for (int o = 32; o; o >>= 1) { num += __shfl_xor(num, o); den += __shfl_xor(den, o); }
      if (tid == 0) out[b*TT + t + 1] = sigm(num/den);
    }
    __syncthreads();
  }
}

extern "C" void kernel_launch(void* const* d_in, const int* in_sizes, int n_in,
                              void* d_out, int out_size, void* d_ws, size_t ws_size,
                              hipStream_t stream) {
  const float* emb_q  = (const float*)d_in[0];
  const float* emb_q2 = (const float*)d_in[1];
  const float* emb_s  = (const float*)d_in[2];
  const float* emb_u  = (const float*)d_in[3];
  const float* emb_r  = (const float*)d_in[4];
  const float* w1_q   = (const float*)d_in[5];
  const float* w2_q   = (const float*)d_in[6];
  const float* lin_W  = (const float*)d_in[7];
  const float* lin_b  = (const float*)d_in[8];
  const float* Wih    = (const float*)d_in[9];
  const float* Whh    = (const float*)d_in[10];
  const float* bih    = (const float*)d_in[11];
  const float* bhh    = (const float*)d_in[12];
  const float* agg_W  = (const float*)d_in[13];
  const float* agg_b  = (const float*)d_in[14];
  const float* last_W = (const float*)d_in[15];
  const float* last_b = (const float*)d_in[16];
  const float* qW     = (const float*)d_in[17];
  const float* qb     = (const float*)d_in[18];
  const float* kW     = (const float*)d_in[19];
  const float* kb     = (const float*)d_in[20];
  const float* wW     = (const float*)d_in[21];
  const float* wb     = (const float*)d_in[22];
  const float* h0     = (const float*)d_in[23];
  const float* c0     = (const float*)d_in[24];
  const int* user      = (const int*)d_in[25];
  const int* question  = (const int*)d_in[26];
  const int* response  = (const int*)d_in[27];
  const int* mask      = (const int*)d_in[28];
  const int* q_nb      = (const int*)d_in[29];
  const int* s_nb      = (const int*)d_in[30];
  const int* u_nb      = (const int*)d_in[31];
  const int* q_nb2     = (const int*)d_in[32];
  const int* qs_skill  = (const int*)d_in[33];

  // bf16 intermediates: total ws = 19072*700*2 + 19072*40 B ≈ 27.5 MB
  __hip_bfloat16* embhat = (__hip_bfloat16*)d_ws;              // NITEM*100
  __hip_bfloat16* xin    = embhat + (size_t)NITEM*100;         // NITEM*200
  __hip_bfloat16* xg     = xin    + (size_t)NITEM*200;         // NITEM*400
  int*            topidx = (int*)(xg + (size_t)NITEM*400);     // NITEM*10

  k_embhat<<<1024, 512, 0, stream>>>(emb_q, emb_q2, emb_s, emb_u, w1_q, w2_q,
                                     agg_W, agg_b, last_W, last_b,
                                     user, question, mask, q_nb, s_nb, u_nb, q_nb2,
                                     embhat);
  k_xin<<<256, 256, 0, stream>>>(emb_r, lin_W, lin_b, response, embhat, xin);
  k_xg<<<dim3(256, 2), 256, 0, stream>>>(Wih, bih, bhh, xin, xg);
  k_topk<<<128, 256, 0, stream>>>(emb_q, question, topidx);
  k_scan<<<128, 512, 0, stream>>>(emb_q, emb_s, Whh, qW, qb, kW, kb, wW, wb,
                                  h0, c0, question, qs_skill, xg, topidx,
                                  (float*)d_out);
}

// Round 4
// 3399.418 us; speedup vs baseline: 1.4428x; 1.4428x over previous
//
#include <hip/hip_runtime.h>
#include <hip/hip_bf16.h>

#define BB 128
#define TT 150
#define DD 100
#define TS 149
#define NITEM (TS*BB)

__device__ __forceinline__ float bf(__hip_bfloat16 x) { return __bfloat162float(x); }
__device__ __forceinline__ __hip_bfloat16 tobf(float x) { return __float2bfloat16(x); }
__device__ __forceinline__ float sigm(float x) { return 1.f / (1.f + expf(-x)); }

// bf16 pack/unpack helpers (RNE)
__device__ __forceinline__ unsigned pk2(float a, float b) {
  unsigned ua = __float_as_uint(a), ub = __float_as_uint(b);
  ua += 0x7fffu + ((ua >> 16) & 1u);
  ub += 0x7fffu + ((ub >> 16) & 1u);
  return (ua >> 16) | (ub & 0xffff0000u);
}
__device__ __forceinline__ float blo(unsigned u) { return __uint_as_float(u << 16); }
__device__ __forceinline__ float bhi(unsigned u) { return __uint_as_float(u & 0xffff0000u); }

// dot of bf16-packed weight column (25 uint2 = 100 k) with f32 LDS row
__device__ __forceinline__ float dotq(const uint2* __restrict__ wq, const float* __restrict__ x) {
  const float4* xq = (const float4*)x;
  float acc = 0.f;
#pragma unroll
  for (int k4 = 0; k4 < 25; k4++) {
    uint2 w = wq[k4]; float4 xv = xq[k4];
    acc += blo(w.x)*xv.x + bhi(w.x)*xv.y + blo(w.y)*xv.z + bhi(w.y)*xv.w;
  }
  return acc;
}
// x = xa + xb elementwise
__device__ __forceinline__ float dotq2(const uint2* __restrict__ wq,
                                       const float* __restrict__ xa, const float* __restrict__ xb) {
  const float4* aq = (const float4*)xa; const float4* bq = (const float4*)xb;
  float acc = 0.f;
#pragma unroll
  for (int k4 = 0; k4 < 25; k4++) {
    uint2 w = wq[k4]; float4 av = aq[k4]; float4 bv = bq[k4];
    acc += blo(w.x)*(av.x+bv.x) + bhi(w.x)*(av.y+bv.y) + blo(w.y)*(av.z+bv.z) + bhi(w.y)*(av.w+bv.w);
  }
  return acc;
}
// x = inv * sum_{r<NR} rows[r*100+..] + x0
template<int NR>
__device__ __forceinline__ float dotq_m(const uint2* __restrict__ wq,
                                        const float* __restrict__ rows, float inv,
                                        const float* __restrict__ x0) {
  const float4* x0q = (const float4*)x0;
  float acc = 0.f;
  for (int k4 = 0; k4 < 25; k4++) {
    uint2 w = wq[k4];
    float sx = 0.f, sy = 0.f, sz = 0.f, sw = 0.f;
#pragma unroll
    for (int r = 0; r < NR; r++) {
      float4 v = ((const float4*)(rows + r*100))[k4];
      sx += v.x; sy += v.y; sz += v.z; sw += v.w;
    }
    float4 b = x0q[k4];
    acc += blo(w.x)*(inv*sx+b.x) + bhi(w.x)*(inv*sy+b.y) + blo(w.y)*(inv*sz+b.z) + bhi(w.y)*(inv*sw+b.w);
  }
  return acc;
}

// scratch offsets (floats)
#define BUFQ  0
#define T1INQ 4000
#define T0INQ 4400
#define M2BQ  4500
#define T1AQ  4900
#define T1BQ  5300
#define T0AQ  5700
#define T0BQ  5800
#define T0CQ  5900
#define BUFU  6000
#define T1INU 11000
#define T0INU 12000
#define M2BU  12100
#define T1AU  13100
#define T1BU  14100
#define T0AU  15100
#define T0BU  15200
#define T0CU  15300
#define SSZ   15400

// ---------------------------------------------------------------------------
// P1: per-(t,b) multi-hop aggregate -> emb_hat  (index-only, fully parallel)
// ---------------------------------------------------------------------------
__global__ __launch_bounds__(512, 1) void k_embhat(
    const float* __restrict__ emb_q, const float* __restrict__ emb_q2,
    const float* __restrict__ emb_s, const float* __restrict__ emb_u,
    const float* __restrict__ w1_q, const float* __restrict__ w2_q,
    const float* __restrict__ agg_W, const float* __restrict__ agg_b,
    const float* __restrict__ last_W, const float* __restrict__ last_b,
    const int* __restrict__ user, const int* __restrict__ question, const int* __restrict__ mask,
    const int* __restrict__ q_nb, const int* __restrict__ s_nb,
    const int* __restrict__ u_nb, const int* __restrict__ q_nb2,
    __hip_bfloat16* __restrict__ embhat)
{
  __shared__ uint2 WQ0[2500], WQ1[2500], WQ2[2500], WQL[2500]; // [c*25+k4], bf16x4 packed
  __shared__ float b0[100], b1[100], b2[100], bl[100];
  __shared__ __align__(16) float S[SSZ];
  __shared__ int n1[4], n2[40], n3[160], m1[10], m2[50], m3[500];
  const int tid = threadIdx.x;
  const float4* eq4  = (const float4*)emb_q;
  const float4* eq24 = (const float4*)emb_q2;
  const float4* es4  = (const float4*)emb_s;
  const float4* eu4  = (const float4*)emb_u;

  for (int i = tid; i < 2500; i += 512) {
    int c = i / 25, k4 = i % 25;
    float4 a;
    a = *(const float4*)&agg_W[c*100 + k4*4];          WQ0[i] = make_uint2(pk2(a.x,a.y), pk2(a.z,a.w));
    a = *(const float4*)&agg_W[10000 + c*100 + k4*4];  WQ1[i] = make_uint2(pk2(a.x,a.y), pk2(a.z,a.w));
    a = *(const float4*)&agg_W[20000 + c*100 + k4*4];  WQ2[i] = make_uint2(pk2(a.x,a.y), pk2(a.z,a.w));
    a = *(const float4*)&last_W[c*100 + k4*4];         WQL[i] = make_uint2(pk2(a.x,a.y), pk2(a.z,a.w));
  }
  if (tid < 100) {
    b0[tid] = agg_b[tid]; b1[tid] = agg_b[100+tid];
    b2[tid] = agg_b[200+tid]; bl[tid] = last_b[tid];
  }
  const float w1 = w1_q[0], w2 = w2_q[0];
  __syncthreads();

  for (int item = blockIdx.x; item < NITEM; item += gridDim.x) {
    const int t = item / BB, b = item % BB;
    const int qt = question[b*TT + t];
    if (mask[b*TT + t] != 1) {
      if (tid < 50) {
        const float2 q = *(const float2*)&emb_q[qt*100 + tid*2];
        const float2 p = *(const float2*)&emb_q2[qt*100 + tid*2];
        ((unsigned*)embhat)[item*50 + tid] = pk2(w1*q.x + w2*p.x, w1*q.y + w2*p.y);
      }
      continue;
    }
    const int ut = user[b*TT + t];
    // ---- index staging (3 dependent levels) ----
    if (tid < 4) n1[tid] = q_nb[qt*4 + tid];
    else if (tid >= 64 && tid < 74) m1[tid-64] = u_nb[ut*10 + (tid-64)];
    __syncthreads();
    if (tid < 40) n2[tid] = s_nb[n1[tid/10]*10 + tid%10];
    else if (tid >= 64 && tid < 114) { int e = tid-64; m2[e] = q_nb2[m1[e/5]*5 + e%5]; }
    __syncthreads();
    for (int i = tid; i < 660; i += 512) {
      if (i < 160) n3[i] = q_nb[n2[i/4]*4 + i%4];
      else { int e = i-160; m3[e] = u_nb[m2[e/10]*10 + e%10]; }
    }
    __syncthreads();
    // ---- phase 1: all gathers (Q + U), float4 granularity ----
    for (int u = tid; u < 2650; u += 512) {
      if (u < 1000) {                       // Q bufA: 40 rows
        int r = u/25, k4 = u%25;
        float4 v0 = es4[n3[r*4+0]*25+k4], v1 = es4[n3[r*4+1]*25+k4];
        float4 v2 = es4[n3[r*4+2]*25+k4], v3 = es4[n3[r*4+3]*25+k4];
        float4 q = eq4[n2[r]*25+k4];
        *(float4*)&S[BUFQ + r*100 + k4*4] = make_float4(
          0.25f*(v0.x+v1.x+v2.x+v3.x)+q.x, 0.25f*(v0.y+v1.y+v2.y+v3.y)+q.y,
          0.25f*(v0.z+v1.z+v2.z+v3.z)+q.z, 0.25f*(v0.w+v1.w+v2.w+v3.w)+q.w);
      } else if (u < 1100) {                // Q t1a_in: 4 rows
        int e = u-1000, a = e/25, k4 = e%25;
        float sx=0,sy=0,sz=0,sw=0;
        for (int j = 0; j < 10; j++) {
          float4 v = eq4[n2[a*10+j]*25+k4]; sx+=v.x; sy+=v.y; sz+=v.z; sw+=v.w;
        }
        float4 h = es4[n1[a]*25+k4];
        *(float4*)&S[T1INQ + a*100 + k4*4] = make_float4(0.1f*sx+h.x, 0.1f*sy+h.y, 0.1f*sz+h.z, 0.1f*sw+h.w);
      } else if (u < 1125) {                // Q t0a_in
        int k4 = u-1100;
        float4 v0 = es4[n1[0]*25+k4], v1 = es4[n1[1]*25+k4];
        float4 v2 = es4[n1[2]*25+k4], v3 = es4[n1[3]*25+k4];
        float4 q = eq4[qt*25+k4];
        *(float4*)&S[T0INQ + k4*4] = make_float4(
          0.25f*(v0.x+v1.x+v2.x+v3.x)+q.x, 0.25f*(v0.y+v1.y+v2.y+v3.y)+q.y,
          0.25f*(v0.z+v1.z+v2.z+v3.z)+q.z, 0.25f*(v0.w+v1.w+v2.w+v3.w)+q.w);
      } else if (u < 2375) {                // U bufA: 50 rows
        int e = u-1125, r = e/25, k4 = e%25;
        float sx=0,sy=0,sz=0,sw=0;
        for (int k = 0; k < 10; k++) {
          float4 v = eq24[m3[r*10+k]*25+k4]; sx+=v.x; sy+=v.y; sz+=v.z; sw+=v.w;
        }
        float4 h = eu4[m2[r]*25+k4];
        *(float4*)&S[BUFU + r*100 + k4*4] = make_float4(0.1f*sx+h.x, 0.1f*sy+h.y, 0.1f*sz+h.z, 0.1f*sw+h.w);
      } else if (u < 2625) {                // U t1a_in: 10 rows
        int e = u-2375, a = e/25, k4 = e%25;
        float sx=0,sy=0,sz=0,sw=0;
        for (int p = 0; p < 5; p++) {
          float4 v = eu4[m2[a*5+p]*25+k4]; sx+=v.x; sy+=v.y; sz+=v.z; sw+=v.w;
        }
        float4 h = eq24[m1[a]*25+k4];
        *(float4*)&S[T1INU + a*100 + k4*4] = make_float4(0.2f*sx+h.x, 0.2f*sy+h.y, 0.2f*sz+h.z, 0.2f*sw+h.w);
      } else {                              // U t0a_in
        int k4 = u-2625;
        float sx=0,sy=0,sz=0,sw=0;
        for (int mm = 0; mm < 10; mm++) {
          float4 v = eq24[m1[mm]*25+k4]; sx+=v.x; sy+=v.y; sz+=v.z; sw+=v.w;
        }
        float4 h = eu4[ut*25+k4];
        *(float4*)&S[T0INU + k4*4] = make_float4(0.1f*sx+h.x, 0.1f*sy+h.y, 0.1f*sz+h.z, 0.1f*sw+h.w);
      }
    }
    __syncthreads();
    // ---- phase 2: first linear level (t2 fused relu+mean, t1a, t0a) ----
    for (int u = tid; u < 3000; u += 512) {
      if (u < 400) {                        // t2-Q -> m2bQ, W hoisted over s
        int a = u/100, c = u%100;
        const uint2* wq = &WQ2[c*25];
        float accs[10];
#pragma unroll
        for (int s = 0; s < 10; s++) accs[s] = 0.f;
        for (int k4 = 0; k4 < 25; k4++) {
          uint2 w = wq[k4];
          float wa = blo(w.x), wb2 = bhi(w.x), wc = blo(w.y), wd = bhi(w.y);
#pragma unroll
          for (int s = 0; s < 10; s++) {
            float4 xv = *(const float4*)&S[BUFQ + (a*10+s)*100 + k4*4];
            accs[s] += wa*xv.x + wb2*xv.y + wc*xv.z + wd*xv.w;
          }
        }
        float acc = 0.f;
#pragma unroll
        for (int s = 0; s < 10; s++) acc += fmaxf(b2[c] + accs[s], 0.f);
        S[M2BQ + a*100 + c] = 0.1f*acc;
      } else if (u < 1400) {                // t2-U -> m2bU
        int e = u-400, a = e/100, c = e%100;
        const uint2* wq = &WQ2[c*25];
        float accs[5];
#pragma unroll
        for (int p = 0; p < 5; p++) accs[p] = 0.f;
        for (int k4 = 0; k4 < 25; k4++) {
          uint2 w = wq[k4];
          float wa = blo(w.x), wb2 = bhi(w.x), wc = blo(w.y), wd = bhi(w.y);
#pragma unroll
          for (int p = 0; p < 5; p++) {
            float4 xv = *(const float4*)&S[BUFU + (a*5+p)*100 + k4*4];
            accs[p] += wa*xv.x + wb2*xv.y + wc*xv.z + wd*xv.w;
          }
        }
        float acc = 0.f;
#pragma unroll
        for (int p = 0; p < 5; p++) acc += fmaxf(b2[c] + accs[p], 0.f);
        S[M2BU + a*100 + c] = 0.2f*acc;
      } else if (u < 1800) {                // t1a-Q
        int e = u-1400, a = e/100, c = e%100;
        S[T1AQ + a*100 + c] = fmaxf(b1[c] + dotq(&WQ1[c*25], &S[T1INQ + a*100]), 0.f);
      } else if (u < 2800) {                // t1a-U
        int e = u-1800, a = e/100, c = e%100;
        S[T1AU + a*100 + c] = fmaxf(b1[c] + dotq(&WQ1[c*25], &S[T1INU + a*100]), 0.f);
      } else if (u < 2900) {                // t0a-Q
        int c = u-2800;
        S[T0AQ + c] = fmaxf(b0[c] + dotq(&WQ0[c*25], &S[T0INQ]), 0.f);
      } else {                              // t0a-U
        int c = u-2900;
        S[T0AU + c] = fmaxf(b0[c] + dotq(&WQ0[c*25], &S[T0INU]), 0.f);
      }
    }
    __syncthreads();
    // ---- phase 3: second level (t1b, t0b) ----
    for (int u = tid; u < 1600; u += 512) {
      if (u < 400) {
        int a = u/100, c = u%100;
        S[T1BQ + a*100 + c] = fmaxf(b1[c] + dotq2(&WQ1[c*25], &S[M2BQ + a*100], &S[T1AQ + a*100]), 0.f);
      } else if (u < 1400) {
        int e = u-400, a = e/100, c = e%100;
        S[T1BU + a*100 + c] = fmaxf(b1[c] + dotq2(&WQ1[c*25], &S[M2BU + a*100], &S[T1AU + a*100]), 0.f);
      } else if (u < 1500) {
        int c = u-1400;
        S[T0BQ + c] = fmaxf(b0[c] + dotq_m<4>(&WQ0[c*25], &S[T1AQ], 0.25f, &S[T0AQ]), 0.f);
      } else {
        int c = u-1500;
        S[T0BU + c] = fmaxf(b0[c] + dotq_m<10>(&WQ0[c*25], &S[T1AU], 0.1f, &S[T0AU]), 0.f);
      }
    }
    __syncthreads();
    // ---- phase 4: t0c ----
    if (tid < 100) {
      int c = tid;
      S[T0CQ + c] = fmaxf(b0[c] + dotq_m<4>(&WQ0[c*25], &S[T1BQ], 0.25f, &S[T0BQ]), 0.f);
    } else if (tid < 200) {
      int c = tid-100;
      S[T0CU + c] = fmaxf(b0[c] + dotq_m<10>(&WQ0[c*25], &S[T1BU], 0.1f, &S[T0BU]), 0.f);
    }
    __syncthreads();
    // ---- phase 5: final linear + combine ----
    if (tid < 100) {
      int c = tid;
      float dq = fmaxf(bl[c] + dotq(&WQL[c*25], &S[T0CQ]), 0.f);
      float du = fmaxf(bl[c] + dotq(&WQL[c*25], &S[T0CU]), 0.f);
      embhat[item*100 + c] = tobf(w1*dq + w2*du);
    }
    __syncthreads();
  }
}

// ---------------------------------------------------------------------------
// P2a: x_in = relu(lin([emb_hat, emb_r[r_t]]))
// ---------------------------------------------------------------------------
__global__ __launch_bounds__(256, 1) void k_xin(
    const float* __restrict__ emb_r, const float* __restrict__ lin_W,
    const float* __restrict__ lin_b, const int* __restrict__ response,
    const __hip_bfloat16* __restrict__ embhat, __hip_bfloat16* __restrict__ xin)
{
  __shared__ __hip_bfloat16 WT[40000];
  __shared__ float xcat[200];
  __shared__ float lb[200];
  const int tid = threadIdx.x;
  for (int i = tid; i < 40000; i += 256) { int j = i/200, k = i%200; WT[k*200+j] = tobf(lin_W[i]); }
  if (tid < 200) lb[tid] = lin_b[tid];
  __syncthreads();
  for (int item = blockIdx.x; item < NITEM; item += gridDim.x) {
    const int t = item / BB, b = item % BB;
    if (tid < 100) xcat[tid] = bf(embhat[item*100 + tid]);
    else if (tid < 200) { int rt = response[b*TT + t]; xcat[tid] = emb_r[rt*100 + tid - 100]; }
    __syncthreads();
    if (tid < 200) {
      float acc = lb[tid];
      for (int k = 0; k < 200; k++) acc += bf(WT[k*200+tid]) * xcat[k];
      xin[item*200 + tid] = tobf(fmaxf(acc, 0.f));
    }
    __syncthreads();
  }
}

// ---------------------------------------------------------------------------
// P2b: xg = x_in @ Wih.T + bih + bhh   (blockIdx.y selects output half)
// ---------------------------------------------------------------------------
__global__ __launch_bounds__(256, 1) void k_xg(
    const float* __restrict__ Wih, const float* __restrict__ bih,
    const float* __restrict__ bhh,
    const __hip_bfloat16* __restrict__ xin, __hip_bfloat16* __restrict__ xg)
{
  __shared__ __hip_bfloat16 WT[40000];
  __shared__ float xv[200];
  __shared__ float bsum[200];
  const int tid = threadIdx.x;
  const int H = blockIdx.y;
  for (int i = tid; i < 40000; i += 256) { int jj = i/200, k = i%200; WT[k*200+jj] = tobf(Wih[H*40000 + i]); }
  if (tid < 200) bsum[tid] = bih[H*200+tid] + bhh[H*200+tid];
  __syncthreads();
  for (int item = blockIdx.x; item < NITEM; item += gridDim.x) {
    if (tid < 200) xv[tid] = bf(xin[item*200 + tid]);
    __syncthreads();
    if (tid < 200) {
      float acc = bsum[tid];
      for (int k = 0; k < 200; k++) acc += bf(WT[k*200+tid]) * xv[k];
      xg[(long)item*400 + H*200 + tid] = tobf(acc);
    }
    __syncthreads();
  }
}

// ---------------------------------------------------------------------------
// P3: per-(b,t) top-10 of dot(eq[question[b,t+1]], eq[question[b,j]]), j<t
// ---------------------------------------------------------------------------
__global__ __launch_bounds__(256, 2) void k_topk(
    const float* __restrict__ emb_q, const int* __restrict__ question,
    int* __restrict__ topidx)
{
  __shared__ float Qb[150*101];
  __shared__ int qid[150];
  __shared__ float tval[1490];
  __shared__ int tidxs[1490];
  const int b = blockIdx.x, tid = threadIdx.x;
  if (tid < 150) qid[tid] = question[b*TT + tid];
  __syncthreads();
  for (int i = tid; i < 15000; i += 256) { int r = i/100, c = i%100; Qb[r*101+c] = emb_q[qid[r]*100+c]; }
  __syncthreads();
  if (tid < TS) {
    const int t = tid;
    float* v = &tval[t*10]; int* ix = &tidxs[t*10];
    for (int p = 0; p < 10; p++) { v[p] = -3.0e38f; ix[p] = 0; }
    const float* qrow = &Qb[(t+1)*101];
    for (int j = 0; j < t; j++) {
      const float* r = &Qb[j*101];
      float s = 0.f;
      for (int k = 0; k < 100; k++) s += qrow[k] * r[k];
      if (s > v[9]) {
        int p = 9;
        while (p > 0 && s > v[p-1]) { v[p] = v[p-1]; ix[p] = ix[p-1]; p--; }
        v[p] = s; ix[p] = j;
      }
    }
    for (int p = 0; p < 10; p++) topidx[(t*BB + b)*10 + p] = ix[p];
  }
}

// ---------------------------------------------------------------------------
// P4: the sequential scan — one block per batch element, everything in LDS.
// ---------------------------------------------------------------------------
__global__ __launch_bounds__(512, 1) void k_scan(
    const float* __restrict__ emb_q, const float* __restrict__ emb_s,
    const float* __restrict__ Whh,
    const float* __restrict__ qW, const float* __restrict__ qb,
    const float* __restrict__ kW, const float* __restrict__ kb,
    const float* __restrict__ wW, const float* __restrict__ wb,
    const float* __restrict__ h0, const float* __restrict__ c0,
    const int* __restrict__ question, const int* __restrict__ qs_skill,
    const __hip_bfloat16* __restrict__ xg, const int* __restrict__ topidx,
    float* __restrict__ out)
{
  __shared__ __hip_bfloat16 WhhT[40000];   // [k][j]
  __shared__ float hist[15000];            // [150][100]; row 0 stays zero forever
  __shared__ float h_l[100], c_l[100], gates[400], partial[100];
  __shared__ float qs_l[500], kv[100], qv[100], skv[150], wvec[200];
  __shared__ float gmat[55], sq_l[5];
  __shared__ int selidx[11];
  __shared__ float scal[4]; // 0:ck 1:cq 2:wb0 3:sk(current h)
  const int b = blockIdx.x, tid = threadIdx.x;
  for (int i = tid; i < 40000; i += 512) { int j = i/100, k = i%100; WhhT[k*400+j] = tobf(Whh[i]); }
  for (int i = tid; i < 15000; i += 512) hist[i] = 0.f;
  if (tid < 200) wvec[tid] = wW[tid];
  if (tid < 150) skv[tid] = 0.f;
  if (tid >= 256 && tid < 356) { h_l[tid-256] = h0[b*100+tid-256]; c_l[tid-256] = c0[b*100+tid-256]; }
  __syncthreads();
  if (tid < 100) {
    float a1 = 0.f, a2 = 0.f;
    for (int c = 0; c < 100; c++) { a1 += kW[c*100+tid] * wvec[100+c]; a2 += qW[c*100+tid] * wvec[c]; }
    kv[tid] = a1; qv[tid] = a2;
  }
  if (tid == 256) {
    float ck = 0.f, cq = 0.f;
    for (int c = 0; c < 100; c++) { ck += kb[c] * wvec[100+c]; cq += qb[c] * wvec[c]; }
    scal[0] = ck; scal[1] = cq; scal[2] = wb[0]; scal[3] = 0.f;
    skv[0] = ck;
    out[b*TT] = 0.5f;
  }
  __syncthreads();
  for (int t = 0; t < TS; t++) {
    if (tid < 400) {
      float acc = bf(xg[((long)t*BB + b)*400 + tid]);
      for (int k = 0; k < 100; k++) acc += bf(WhhT[k*400+tid]) * h_l[k];
      gates[tid] = acc;
    }
    __syncthreads();
    if (tid < 100) {
      float cc = sigm(gates[100+tid])*c_l[tid] + sigm(gates[tid])*tanhf(gates[200+tid]);
      c_l[tid] = cc;
      float hn = sigm(gates[300+tid])*tanhf(cc);
      h_l[tid] = hn;
      if (t > 0) hist[t*100+tid] = hn;
      partial[tid] = hn * kv[tid];
    }
    __syncthreads();
    if (tid < 64) {
      float v = partial[tid] + ((tid < 36) ? partial[tid+64] : 0.f);
#pragma unroll
      for (int o = 32; o; o >>= 1) v += __shfl_xor(v, o);
      if (tid == 0) { float s = v + scal[0]; scal[3] = s; if (t > 0) skv[t] = s; }
    } else {
      const int qn = question[b*TT + t + 1];
      for (int e = tid - 64; e < 500; e += 448) {
        int q = e / 100, c = e % 100;
        qs_l[e] = (q == 0) ? emb_q[qn*100 + c] : emb_s[qs_skill[qn*4 + q - 1]*100 + c];
      }
      if (tid < 75) {
        int p = tid - 64;
        if (p == 0) selidx[0] = -2;
        else {
          int pp = p - 1;
          int cnt = t < 10 ? t : 10;
          selidx[p] = (pp < cnt) ? topidx[((long)t*BB + b)*10 + pp] : -1;
        }
      }
    }
    __syncthreads();
    {
      int u = tid >> 2, l4 = tid & 3;
      if (u < 60) {
        const float* row;
        int q;
        const bool isG = (u < 55);
        if (isG) {
          q = u / 11;
          int s = u % 11;
          int j = (s == 0) ? 0 : selidx[s];
          if (j < 0) j = 0;
          row = (s == 0) ? h_l : &hist[j*100];
        } else { q = u - 55; row = qv; }
        float part = 0.f;
        for (int k = l4*25; k < l4*25+25; k++) part += qs_l[q*100+k] * row[k];
        part += __shfl_xor(part, 1);
        part += __shfl_xor(part, 2);
        if (l4 == 0) { if (isG) gmat[u] = part; else sq_l[q] = part + scal[1]; }
      }
    }
    __syncthreads();
    if (tid < 64) {
      const bool has = (tid < 55);
      int q = has ? tid/11 : 0, s = has ? tid%11 : 0;
      int j = (s == 0) ? 0 : selidx[s];
      bool valid = has && ((s == 0) || (j >= 0));
      if (j < 0) j = 0;
      float sk = (s == 0) ? scal[3] : skv[j];
      float sc = valid ? (sq_l[q] + sk + scal[2]) : -1e9f;
      float gv = has ? gmat[tid] : 0.f;
      float m = sc;
#pragma unroll
      for (int o = 32; o; o >>= 1) m = fmaxf(m, __shfl_xor(m, o));
      float ex = has ? expf(sc - m) : 0.f;
      float num = ex * gv, den = ex;
#pragma unroll
      for (int o = 32; o; o >>= 1) { num += __shfl_xor(num, o); den += __shfl_xor(den, o); }
      if (tid == 0) out[b*TT + t + 1] = sigm(num/den);
    }
    __syncthreads();
  }
}

extern "C" void kernel_launch(void* const* d_in, const int* in_sizes, int n_in,
                              void* d_out, int out_size, void* d_ws, size_t ws_size,
                              hipStream_t stream) {
  const float* emb_q  = (const float*)d_in[0];
  const float* emb_q2 = (const float*)d_in[1];
  const float* emb_s  = (const float*)d_in[2];
  const float* emb_u  = (const float*)d_in[3];
  const float* emb_r  = (const float*)d_in[4];
  const float* w1_q   = (const float*)d_in[5];
  const float* w2_q   = (const float*)d_in[6];
  const float* lin_W  = (const float*)d_in[7];
  const float* lin_b  = (const float*)d_in[8];
  const float* Wih    = (const float*)d_in[9];
  const float* Whh    = (const float*)d_in[10];
  const float* bih    = (const float*)d_in[11];
  const float* bhh    = (const float*)d_in[12];
  const float* agg_W  = (const float*)d_in[13];
  const float* agg_b  = (const float*)d_in[14];
  const float* last_W = (const float*)d_in[15];
  const float* last_b = (const float*)d_in[16];
  const float* qW     = (const float*)d_in[17];
  const float* qb     = (const float*)d_in[18];
  const float* kW     = (const float*)d_in[19];
  const float* kb     = (const float*)d_in[20];
  const float* wW     = (const float*)d_in[21];
  const float* wb     = (const float*)d_in[22];
  const float* h0     = (const float*)d_in[23];
  const float* c0     = (const float*)d_in[24];
  const int* user      = (const int*)d_in[25];
  const int* question  = (const int*)d_in[26];
  const int* response  = (const int*)d_in[27];
  const int* mask      = (const int*)d_in[28];
  const int* q_nb      = (const int*)d_in[29];
  const int* s_nb      = (const int*)d_in[30];
  const int* u_nb      = (const int*)d_in[31];
  const int* q_nb2     = (const int*)d_in[32];
  const int* qs_skill  = (const int*)d_in[33];

  __hip_bfloat16* embhat = (__hip_bfloat16*)d_ws;              // NITEM*100
  __hip_bfloat16* xin    = embhat + (size_t)NITEM*100;         // NITEM*200
  __hip_bfloat16* xg     = xin    + (size_t)NITEM*200;         // NITEM*400
  int*            topidx = (int*)(xg + (size_t)NITEM*400);     // NITEM*10

  k_embhat<<<1024, 512, 0, stream>>>(emb_q, emb_q2, emb_s, emb_u, w1_q, w2_q,
                                     agg_W, agg_b, last_W, last_b,
                                     user, question, mask, q_nb, s_nb, u_nb, q_nb2,
                                     embhat);
  k_xin<<<256, 256, 0, stream>>>(emb_r, lin_W, lin_b, response, embhat, xin);
  k_xg<<<dim3(256, 2), 256, 0, stream>>>(Wih, bih, bhh, xin, xg);
  k_topk<<<128, 256, 0, stream>>>(emb_q, question, topidx);
  k_scan<<<128, 512, 0, stream>>>(emb_q, emb_s, Whh, qW, qb, kW, kb, wW, wb,
                                  h0, c0, question, qs_skill, xg, topidx,
                                  (float*)d_out);
}